// Round 10
// baseline (275.043 us; speedup 1.0000x reference)
//
#include <hip/hip_runtime.h>
#include <hip/hip_bf16.h>

// Sizes (fixed): B=2, S=2048, D=1024, H=16, Hd=64
#define SEQ    2048
#define DMODEL 1024
#define NHEAD  16
#define HDIM   64
#define BATCH  2
#define NTOK   (BATCH * SEQ)           // 4096

#define N_X   (NTOK * DMODEL)
#define N_WQ  (3 * DMODEL * DMODEL)
#define N_BQ  (3 * DMODEL)
#define N_WO  (DMODEL * DMODEL)
#define N_BO  (DMODEL)
#define N_CANON (N_X + N_WQ + N_BQ + N_WO + N_BO)   // 8,392,704

#define NEG_SENT (-1.0e30f)
#define QSCALE 0.1803368801111f        // (1/8) * log2(e)

// split-K attention geometry: 32-q-row blocks, 512-key segments
#define SEGKEYS 512
#define SLOTS_PER_BH 160               // sum over qb of (1 + qb/16)
#define NUNITS (32 * SLOTS_PER_BH)     // 5120 compute units, no dead waves

typedef __attribute__((ext_vector_type(8))) short short8;
typedef __attribute__((ext_vector_type(4))) short short4v;
typedef __attribute__((ext_vector_type(4))) float f32x4;

#define MFMA_BF16(A, B, C) __builtin_amdgcn_mfma_f32_16x16x32_bf16((A), (B), (C), 0, 0, 0)

static __device__ __forceinline__ short8 load8(const __hip_bfloat16* p) {
    return *(const short8*)p;
}

static __device__ __forceinline__ void async16(const void* g, void* l) {
    __builtin_amdgcn_global_load_lds(
        (const __attribute__((address_space(1))) unsigned int*)g,
        (__attribute__((address_space(3))) unsigned int*)l,
        16, 0, 0);
}

// packed slot index: cum = sum_{j<qb} (1 + j/16)
static __device__ __forceinline__ int cumseg(int qb) {
    const int k = qb >> 4;
    return qb + 8 * k * (k - 1) + (qb - (k << 4)) * k;
}

// ---------------------------------------------------------------------------
// Kernel 0: dtype detector (confirmed fp32 in round 2; keep for robustness)
// ---------------------------------------------------------------------------
__global__ void detect_kernel(const unsigned short* __restrict__ w, int* flag) {
    int cnt = 0;
    for (int i = threadIdx.x; i < 512; i += 64) {
        const unsigned e = (w[i] >> 7) & 0xFF;
        if (e >= 125) cnt++;
    }
#pragma unroll
    for (int o = 32; o; o >>= 1) cnt += __shfl_down(cnt, o);
    if (threadIdx.x == 0) *flag = (cnt > 8) ? 1 : 0;
}

// ---------------------------------------------------------------------------
// Kernel 0b: canonicalize inputs to bf16: [X | Wqkv | bqkv | Wout | bout]
// ---------------------------------------------------------------------------
__global__ __launch_bounds__(256) void canon_kernel(
    const void* __restrict__ s0, const void* __restrict__ s1,
    const void* __restrict__ s2, const void* __restrict__ s3,
    const void* __restrict__ s4,
    __hip_bfloat16* __restrict__ dst, const int* __restrict__ flag)
{
    const int idx = blockIdx.x * 256 + threadIdx.x;
    if (idx >= N_CANON) return;
    const void* src;
    int off;
    if (idx < N_X)                         { src = s0; off = idx; }
    else if (idx < N_X + N_WQ)             { src = s1; off = idx - N_X; }
    else if (idx < N_X + N_WQ + N_BQ)      { src = s2; off = idx - (N_X + N_WQ); }
    else if (idx < N_X + N_WQ + N_BQ + N_WO){ src = s3; off = idx - (N_X + N_WQ + N_BQ); }
    else                                   { src = s4; off = idx - (N_X + N_WQ + N_BQ + N_WO); }
    const bool isf32 = (*flag != 0);
    const float v = isf32 ? ((const float*)src)[off]
                          : __bfloat162float(((const __hip_bfloat16*)src)[off]);
    dst[idx] = __float2bfloat16(v);
}

// ---------------------------------------------------------------------------
// Kernel 1: QKV GEMM, m97 structure (128x128 tile, global_load_lds w=16).
// ---------------------------------------------------------------------------
__global__ __launch_bounds__(256) void qkv_gemm_kernel(
    const __hip_bfloat16* __restrict__ X,
    const __hip_bfloat16* __restrict__ W,
    const __hip_bfloat16* __restrict__ bias,
    __hip_bfloat16* __restrict__ Qs,
    __hip_bfloat16* __restrict__ Kb,
    __hip_bfloat16* __restrict__ Vt)
{
    constexpr int Kd = DMODEL;
    __shared__ __align__(16) __hip_bfloat16 As[128 * 32];
    __shared__ __align__(16) __hip_bfloat16 Bs[128 * 32];

    const int tid   = threadIdx.x;
    const int lane  = tid & 63;
    const int w     = tid >> 6;
    const int mTile = blockIdx.y * 128;
    const int nTile = blockIdx.x * 128;
    const int wm    = (w >> 1) * 64;
    const int wn    = (w & 1) * 64;
    const int lm    = lane & 15;
    const int lk    = (lane >> 4) * 8;

    f32x4 acc[4][4];
#pragma unroll
    for (int i = 0; i < 4; ++i)
#pragma unroll
        for (int j = 0; j < 4; ++j)
            acc[i][j] = (f32x4){0.f, 0.f, 0.f, 0.f};

    const int r0c = tid >> 2, p0c = tid & 3;
    const int r1c = (tid + 256) >> 2, p1c = tid & 3;

    for (int k0 = 0; k0 < Kd; k0 += 32) {
        __syncthreads();
        async16(&X[(size_t)(mTile + r0c) * Kd + k0 + p0c * 8], (char*)As + tid * 16);
        async16(&X[(size_t)(mTile + r1c) * Kd + k0 + p1c * 8], (char*)As + tid * 16 + 4096);
        async16(&W[(size_t)(nTile + r0c) * Kd + k0 + p0c * 8], (char*)Bs + tid * 16);
        async16(&W[(size_t)(nTile + r1c) * Kd + k0 + p1c * 8], (char*)Bs + tid * 16 + 4096);
        __syncthreads();

        short8 a[4], b[4];
#pragma unroll
        for (int i = 0; i < 4; ++i)
            a[i] = *(const short8*)&As[(wm + i * 16 + lm) * 32 + lk];
#pragma unroll
        for (int j = 0; j < 4; ++j)
            b[j] = *(const short8*)&Bs[(wn + j * 16 + lm) * 32 + lk];
#pragma unroll
        for (int i = 0; i < 4; ++i)
#pragma unroll
            for (int j = 0; j < 4; ++j)
                acc[i][j] = MFMA_BF16(a[i], b[j], acc[i][j]);
    }

    const int r0 = (lane >> 4) * 4;
#pragma unroll
    for (int j = 0; j < 4; ++j) {
        const int n  = nTile + wn + j * 16 + lm;
        const float bv = __bfloat162float(bias[n]);
        const int c = n >> 10;
        const int h = (n >> 6) & 15;
        const int d = n & 63;
#pragma unroll
        for (int i = 0; i < 4; ++i) {
#pragma unroll
            for (int r = 0; r < 4; ++r) {
                const int m  = mTile + wm + i * 16 + r0 + r;
                const int bb = m >> 11;
                const int s  = m & (SEQ - 1);
                const int bh = bb * NHEAD + h;
                const float v = acc[i][j][r] + bv;
                if (c == 0) {
                    Qs[(size_t)(bh * SEQ + s) * HDIM + d] = __float2bfloat16(v * QSCALE);
                } else if (c == 1) {
                    Kb[(size_t)(bh * SEQ + s) * HDIM + d] = __float2bfloat16(v);
                } else {
                    Vt[(size_t)(bh * HDIM + d) * SEQ + s] = __float2bfloat16(v);
                }
            }
        }
    }
}

// ---------------------------------------------------------------------------
// Kernel 2a: split-K flash attention, COMPACT unit list, 8 waves/workgroup.
// 512 threads = 8 independent waves (private LDS slabs, no barriers).
// unit u = blockIdx.x*8 + wave; u in [0, 5120): bh = u&31, rank = u>>5,
// s' = 159-rank decoded to (qb, seg) heavy-first.  All units <=8 chunks;
// a WG's 8 waves share one rank -> near-uniform finish.
// __launch_bounds__(512,2): VGPR cap 128 (kernel ~108, no spill — round 7/8
// evidence), residency ceiling 2 WGs x 8 waves = 16 waves/CU.
// ---------------------------------------------------------------------------
#define P_PITCH 72
template <typename T>
__global__ __launch_bounds__(512, 2) void attn_seg_kernel(
    const __hip_bfloat16* __restrict__ Qs,
    const __hip_bfloat16* __restrict__ Kb,
    const __hip_bfloat16* __restrict__ Vt,
    T* __restrict__ Po,          // [5120][2048]
    float* __restrict__ Pm,      // [5120][32]
    float* __restrict__ Pl)      // [5120][32]
{
    __shared__ __align__(16) __hip_bfloat16 Pall[8][32 * P_PITCH];

    const int lane = threadIdx.x & 63;
    const int wv   = threadIdx.x >> 6;
    const int u    = blockIdx.x * 8 + wv;   // 0..5119, 0 = heaviest
    const int bh   = u & 31;
    const int sp   = 159 - (u >> 5);        // ascending slot id 0..159
    int qb, seg;
    if (sp < 16)      { qb = sp;                 seg = 0; }
    else if (sp < 48) { const int t = sp - 16;   qb = 16 + (t >> 1); seg = t & 1; }
    else if (sp < 96) { const int t = sp - 48;   const int q = t / 3; qb = 32 + q; seg = t - 3 * q; }
    else              { const int t = sp - 96;   qb = 48 + (t >> 2); seg = t & 3; }

    __hip_bfloat16* P = Pall[wv];

    const int base  = qb * 32;
    const int kbeg  = seg * SEGKEYS;
    const int kcnt  = min(SEGKEYS, base + 32 - kbeg);
    const int nCh   = (kcnt + 63) >> 6;

    const int lm  = lane & 15;
    const int q4  = lane >> 4;
    const int lk  = q4 * 8;
    const int swz = (lm & 3) << 4;

    const __hip_bfloat16* Qbh = Qs + (size_t)bh * SEQ * HDIM;
    const __hip_bfloat16* Kbh = Kb + (size_t)bh * SEQ * HDIM;
    const __hip_bfloat16* Vbh = Vt + (size_t)bh * HDIM * SEQ;

    short8 qa[2][2];
#pragma unroll
    for (int i = 0; i < 2; ++i)
#pragma unroll
        for (int h = 0; h < 2; ++h)
            qa[i][h] = load8(&Qbh[(size_t)(base + i * 16 + lm) * HDIM + h * 32 + lk]);

    float m_run[2] = {NEG_SENT, NEG_SENT};
    float l_run[2] = {0.f, 0.f};
    f32x4 Oacc[2][4];
#pragma unroll
    for (int i = 0; i < 2; ++i)
#pragma unroll
        for (int t = 0; t < 4; ++t) Oacc[i][t] = (f32x4){0.f, 0.f, 0.f, 0.f};

    short8 ka[4][2];
#pragma unroll
    for (int t = 0; t < 4; ++t)
#pragma unroll
        for (int h = 0; h < 2; ++h)
            ka[t][h] = load8(&Kbh[(size_t)(kbeg + t * 16 + lm) * HDIM + h * 32 + lk]);

    for (int c = 0; c < nCh; ++c) {
        const int k0 = kbeg + c * 64;

        short8 vb[4][2];
#pragma unroll
        for (int t = 0; t < 4; ++t)
#pragma unroll
            for (int h = 0; h < 2; ++h)
                vb[t][h] = load8(&Vbh[(size_t)(t * 16 + lm) * SEQ + k0 + h * 32 + lk]);

        f32x4 sc[2][4];
#pragma unroll
        for (int i = 0; i < 2; ++i)
#pragma unroll
            for (int t = 0; t < 4; ++t) sc[i][t] = (f32x4){0.f, 0.f, 0.f, 0.f};
#pragma unroll
        for (int t = 0; t < 4; ++t)
#pragma unroll
            for (int i = 0; i < 2; ++i) {
                sc[i][t] = MFMA_BF16(ka[t][0], qa[i][0], sc[i][t]);
                sc[i][t] = MFMA_BF16(ka[t][1], qa[i][1], sc[i][t]);
            }

        const int k0n = (c + 1 < nCh) ? k0 + 64 : k0;
        short8 kn[4][2];
#pragma unroll
        for (int t = 0; t < 4; ++t)
#pragma unroll
            for (int h = 0; h < 2; ++h)
                kn[t][h] = load8(&Kbh[(size_t)(k0n + t * 16 + lm) * HDIM + h * 32 + lk]);

        if (k0 + 63 > base) {   // only chunks at/after the diagonal
#pragma unroll
            for (int i = 0; i < 2; ++i) {
                const int row = base + i * 16 + lm;
#pragma unroll
                for (int t = 0; t < 4; ++t)
#pragma unroll
                    for (int r = 0; r < 4; ++r) {
                        const int key = k0 + t * 16 + q4 * 4 + r;
                        if (key > row) sc[i][t][r] = NEG_SENT;
                    }
            }
        }

        float alpha[2];
#pragma unroll
        for (int i = 0; i < 2; ++i) {
            float mx = sc[i][0][0];
#pragma unroll
            for (int t = 0; t < 4; ++t)
#pragma unroll
                for (int r = 0; r < 4; ++r) mx = fmaxf(mx, sc[i][t][r]);
            mx = fmaxf(mx, __shfl_xor(mx, 16));
            mx = fmaxf(mx, __shfl_xor(mx, 32));
            const float mn = fmaxf(m_run[i], mx);
            alpha[i] = exp2f(m_run[i] - mn);
            float s = 0.f;
#pragma unroll
            for (int t = 0; t < 4; ++t)
#pragma unroll
                for (int r = 0; r < 4; ++r) {
                    const float p = exp2f(sc[i][t][r] - mn);
                    sc[i][t][r] = p;
                    s += p;
                }
            s += __shfl_xor(s, 16);
            s += __shfl_xor(s, 32);
            l_run[i] = l_run[i] * alpha[i] + s;
            m_run[i] = mn;
        }

#pragma unroll
        for (int i = 0; i < 2; ++i)
#pragma unroll
            for (int r = 0; r < 4; ++r) {
                const float av = __shfl(alpha[i], q4 * 4 + r);
#pragma unroll
                for (int t = 0; t < 4; ++t) Oacc[i][t][r] *= av;
            }

#pragma unroll
        for (int i = 0; i < 2; ++i)
#pragma unroll
            for (int t = 0; t < 4; ++t) {
                short4v pk;
#pragma unroll
                for (int r = 0; r < 4; ++r)
                    pk[r] = (short)__bfloat16_as_ushort(__float2bfloat16(sc[i][t][r]));
                const int col = (t * 16 + q4 * 4) ^ swz;
                *(short4v*)&P[(i * 16 + lm) * P_PITCH + col] = pk;
            }

#pragma unroll
        for (int h = 0; h < 2; ++h) {
            short8 pa[2];
#pragma unroll
            for (int i = 0; i < 2; ++i) {
                const int col = (h * 32 + lk) ^ swz;
                pa[i] = *(const short8*)&P[(i * 16 + lm) * P_PITCH + col];
            }
#pragma unroll
            for (int t = 0; t < 4; ++t)
#pragma unroll
                for (int i = 0; i < 2; ++i)
                    Oacc[i][t] = MFMA_BF16(pa[i], vb[t][h], Oacc[i][t]);
        }

#pragma unroll
        for (int t = 0; t < 4; ++t)
#pragma unroll
            for (int h = 0; h < 2; ++h) ka[t][h] = kn[t][h];
    }

    // --- write partials (unnormalized) ---
    const int slot = bh * SLOTS_PER_BH + cumseg(qb) + seg;
    T* po = Po + (size_t)slot * 2048;
#pragma unroll
    for (int i = 0; i < 2; ++i)
#pragma unroll
        for (int t = 0; t < 4; ++t)
#pragma unroll
            for (int r = 0; r < 4; ++r) {
                const int off = (i * 16 + q4 * 4 + r) * 64 + t * 16 + lm;
                const float v = Oacc[i][t][r];
                if constexpr (sizeof(T) == 4) po[off] = v;
                else po[off] = (T)__bfloat16_as_ushort(__float2bfloat16(v));
            }
    if (q4 == 0) {
#pragma unroll
        for (int i = 0; i < 2; ++i) {
            Pm[slot * 32 + i * 16 + lm] = m_run[i];
            Pl[slot * 32 + i * 16 + lm] = l_run[i];
        }
    }
}

// ---------------------------------------------------------------------------
// Kernel 2b: combine <=4 segment partials per (bh, qb) -> Ao (bf16).
// ---------------------------------------------------------------------------
template <typename T>
__global__ __launch_bounds__(64) void attn_combine_kernel(
    const T* __restrict__ Po, const float* __restrict__ Pm,
    const float* __restrict__ Pl, __hip_bfloat16* __restrict__ O)
{
    const int qb = blockIdx.x;
    const int bh = blockIdx.y;
    const int nseg = 1 + (qb >> 4);
    const int slot0 = bh * SLOTS_PER_BH + cumseg(qb);
    const int t  = threadIdx.x;
    const int r  = t >> 1;
    const int ch = (t & 1) * 32;

    float mseg[4];
    float M = NEG_SENT;
    for (int s = 0; s < nseg; ++s) {
        mseg[s] = Pm[(slot0 + s) * 32 + r];
        M = fmaxf(M, mseg[s]);
    }
    float L = 0.f;
    float acc[32];
#pragma unroll
    for (int j = 0; j < 32; ++j) acc[j] = 0.f;

    for (int s = 0; s < nseg; ++s) {
        const float f = exp2f(mseg[s] - M);
        L += Pl[(slot0 + s) * 32 + r] * f;
        const T* src = Po + (size_t)(slot0 + s) * 2048 + r * 64 + ch;
        if constexpr (sizeof(T) == 4) {
#pragma unroll
            for (int j = 0; j < 32; j += 4) {
                const f32x4 v = *(const f32x4*)(src + j);
#pragma unroll
                for (int k = 0; k < 4; ++k) acc[j + k] += f * v[k];
            }
        } else {
#pragma unroll
            for (int j = 0; j < 32; j += 4) {
                const short4v v = *(const short4v*)(src + j);
#pragma unroll
                for (int k = 0; k < 4; ++k)
                    acc[j + k] += f * __uint_as_float(((unsigned)(unsigned short)v[k]) << 16);
            }
        }
    }

    const float inv = 1.0f / L;
    const int b = bh >> 4, hh = bh & 15;
    __hip_bfloat16* dst = O + ((size_t)(b * SEQ + qb * 32 + r)) * DMODEL + hh * 64 + ch;
#pragma unroll
    for (int j = 0; j < 32; j += 4) {
        short4v pk;
#pragma unroll
        for (int k = 0; k < 4; ++k)
            pk[k] = (short)__bfloat16_as_ushort(__float2bfloat16(acc[j + k] * inv));
        *(short4v*)(dst + j) = pk;
    }
}

// ---------------------------------------------------------------------------
// Kernel 2 (fallback, ws too small): single-pass attention (round 5).
// ---------------------------------------------------------------------------
__global__ __launch_bounds__(64, 2) void attn_kernel(
    const __hip_bfloat16* __restrict__ Qs,
    const __hip_bfloat16* __restrict__ Kb,
    const __hip_bfloat16* __restrict__ Vt,
    __hip_bfloat16* __restrict__ O)
{
    __shared__ __align__(16) __hip_bfloat16 P[32 * P_PITCH];

    const int lane = threadIdx.x;
    const int qb   = gridDim.x - 1 - blockIdx.x;
    const int bh   = blockIdx.y;
    const int base = qb * 32;
    const int lm   = lane & 15;
    const int q4   = lane >> 4;
    const int lk   = q4 * 8;
    const int swz  = (lm & 3) << 4;

    const __hip_bfloat16* Qbh = Qs + (size_t)bh * SEQ * HDIM;
    const __hip_bfloat16* Kbh = Kb + (size_t)bh * SEQ * HDIM;
    const __hip_bfloat16* Vbh = Vt + (size_t)bh * HDIM * SEQ;

    short8 qa[2][2];
#pragma unroll
    for (int i = 0; i < 2; ++i)
#pragma unroll
        for (int h = 0; h < 2; ++h)
            qa[i][h] = load8(&Qbh[(size_t)(base + i * 16 + lm) * HDIM + h * 32 + lk]);

    float m_run[2] = {NEG_SENT, NEG_SENT};
    float l_run[2] = {0.f, 0.f};
    f32x4 Oacc[2][4];
#pragma unroll
    for (int i = 0; i < 2; ++i)
#pragma unroll
        for (int t = 0; t < 4; ++t) Oacc[i][t] = (f32x4){0.f, 0.f, 0.f, 0.f};

    const int nChunks = (base + 32 + 63) >> 6;

    short8 ka[4][2];
#pragma unroll
    for (int t = 0; t < 4; ++t)
#pragma unroll
        for (int h = 0; h < 2; ++h)
            ka[t][h] = load8(&Kbh[(size_t)(t * 16 + lm) * HDIM + h * 32 + lk]);

    for (int c = 0; c < nChunks; ++c) {
        const int k0 = c * 64;

        short8 vb[4][2];
#pragma unroll
        for (int t = 0; t < 4; ++t)
#pragma unroll
            for (int h = 0; h < 2; ++h)
                vb[t][h] = load8(&Vbh[(size_t)(t * 16 + lm) * SEQ + k0 + h * 32 + lk]);

        f32x4 sc[2][4];
#pragma unroll
        for (int i = 0; i < 2; ++i)
#pragma unroll
            for (int t = 0; t < 4; ++t) sc[i][t] = (f32x4){0.f, 0.f, 0.f, 0.f};
#pragma unroll
        for (int t = 0; t < 4; ++t)
#pragma unroll
            for (int i = 0; i < 2; ++i) {
                sc[i][t] = MFMA_BF16(ka[t][0], qa[i][0], sc[i][t]);
                sc[i][t] = MFMA_BF16(ka[t][1], qa[i][1], sc[i][t]);
            }

        const int k0n = (c + 1 < nChunks) ? k0 + 64 : k0;
        short8 kn[4][2];
#pragma unroll
        for (int t = 0; t < 4; ++t)
#pragma unroll
            for (int h = 0; h < 2; ++h)
                kn[t][h] = load8(&Kbh[(size_t)(k0n + t * 16 + lm) * HDIM + h * 32 + lk]);

        if (k0 + 63 > base) {
#pragma unroll
            for (int i = 0; i < 2; ++i) {
                const int row = base + i * 16 + lm;
#pragma unroll
                for (int t = 0; t < 4; ++t)
#pragma unroll
                    for (int r = 0; r < 4; ++r) {
                        const int key = k0 + t * 16 + q4 * 4 + r;
                        if (key > row) sc[i][t][r] = NEG_SENT;
                    }
            }
        }

        float alpha[2];
#pragma unroll
        for (int i = 0; i < 2; ++i) {
            float mx = sc[i][0][0];
#pragma unroll
            for (int t = 0; t < 4; ++t)
#pragma unroll
                for (int r = 0; r < 4; ++r) mx = fmaxf(mx, sc[i][t][r]);
            mx = fmaxf(mx, __shfl_xor(mx, 16));
            mx = fmaxf(mx, __shfl_xor(mx, 32));
            const float mn = fmaxf(m_run[i], mx);
            alpha[i] = exp2f(m_run[i] - mn);
            float s = 0.f;
#pragma unroll
            for (int t = 0; t < 4; ++t)
#pragma unroll
                for (int r = 0; r < 4; ++r) {
                    const float p = exp2f(sc[i][t][r] - mn);
                    sc[i][t][r] = p;
                    s += p;
                }
            s += __shfl_xor(s, 16);
            s += __shfl_xor(s, 32);
            l_run[i] = l_run[i] * alpha[i] + s;
            m_run[i] = mn;
        }

#pragma unroll
        for (int i = 0; i < 2; ++i)
#pragma unroll
            for (int r = 0; r < 4; ++r) {
                const float av = __shfl(alpha[i], q4 * 4 + r);
#pragma unroll
                for (int t = 0; t < 4; ++t) Oacc[i][t][r] *= av;
            }

#pragma unroll
        for (int i = 0; i < 2; ++i)
#pragma unroll
            for (int t = 0; t < 4; ++t) {
                short4v pk;
#pragma unroll
                for (int r = 0; r < 4; ++r)
                    pk[r] = (short)__bfloat16_as_ushort(__float2bfloat16(sc[i][t][r]));
                const int col = (t * 16 + q4 * 4) ^ swz;
                *(short4v*)&P[(i * 16 + lm) * P_PITCH + col] = pk;
            }

#pragma unroll
        for (int h = 0; h < 2; ++h) {
            short8 pa[2];
#pragma unroll
            for (int i = 0; i < 2; ++i) {
                const int col = (h * 32 + lk) ^ swz;
                pa[i] = *(const short8*)&P[(i * 16 + lm) * P_PITCH + col];
            }
#pragma unroll
            for (int t = 0; t < 4; ++t)
#pragma unroll
                for (int i = 0; i < 2; ++i)
                    Oacc[i][t] = MFMA_BF16(pa[i], vb[t][h], Oacc[i][t]);
        }

#pragma unroll
        for (int t = 0; t < 4; ++t)
#pragma unroll
            for (int h = 0; h < 2; ++h) ka[t][h] = kn[t][h];
    }

    const int b = bh >> 4;
    const int hh = bh & 15;
#pragma unroll
    for (int i = 0; i < 2; ++i)
#pragma unroll
        for (int r = 0; r < 4; ++r) {
            const float lv = __shfl(l_run[i], q4 * 4 + r);
            const float inv = 1.0f / lv;
            const size_t m = (size_t)b * SEQ + base + i * 16 + q4 * 4 + r;
#pragma unroll
            for (int t = 0; t < 4; ++t)
                O[m * DMODEL + hh * 64 + t * 16 + lm] = __float2bfloat16(Oacc[i][t][r] * inv);
        }
}

// ---------------------------------------------------------------------------
// Kernel 3: out projection, m97 structure.
// ---------------------------------------------------------------------------
__global__ __launch_bounds__(256) void proj_gemm_kernel(
    const __hip_bfloat16* __restrict__ A,
    const __hip_bfloat16* __restrict__ W,
    const __hip_bfloat16* __restrict__ bias,
    void* __restrict__ outv,
    const int* __restrict__ flag)
{
    constexpr int Kd = DMODEL;
    __shared__ __align__(16) __hip_bfloat16 As[128 * 32];
    __shared__ __align__(16) __hip_bfloat16 Bs[128 * 32];

    const int tid   = threadIdx.x;
    const int lane  = tid & 63;
    const int w     = tid >> 6;
    const int mTile = blockIdx.y * 128;
    const int nTile = blockIdx.x * 128;
    const int wm    = (w >> 1) * 64;
    const int wn    = (w & 1) * 64;
    const int lm    = lane & 15;
    const int lk    = (lane >> 4) * 8;
    const bool f32out = (*flag != 0);

    f32x4 acc[4][4];
#pragma unroll
    for (int i = 0; i < 4; ++i)
#pragma unroll
        for (int j = 0; j < 4; ++j)
            acc[i][j] = (f32x4){0.f, 0.f, 0.f, 0.f};

    const int r0c = tid >> 2, p0c = tid & 3;
    const int r1c = (tid + 256) >> 2, p1c = tid & 3;

    for (int k0 = 0; k0 < Kd; k0 += 32) {
        __syncthreads();
        async16(&A[(size_t)(mTile + r0c) * Kd + k0 + p0c * 8], (char*)As + tid * 16);
        async16(&A[(size_t)(mTile + r1c) * Kd + k0 + p1c * 8], (char*)As + tid * 16 + 4096);
        async16(&W[(size_t)(nTile + r0c) * Kd + k0 + p0c * 8], (char*)Bs + tid * 16);
        async16(&W[(size_t)(nTile + r1c) * Kd + k0 + p1c * 8], (char*)Bs + tid * 16 + 4096);
        __syncthreads();

        short8 a[4], b[4];
#pragma unroll
        for (int i = 0; i < 4; ++i)
            a[i] = *(const short8*)&As[(wm + i * 16 + lm) * 32 + lk];
#pragma unroll
        for (int j = 0; j < 4; ++j)
            b[j] = *(const short8*)&Bs[(wn + j * 16 + lm) * 32 + lk];
#pragma unroll
        for (int i = 0; i < 4; ++i)
#pragma unroll
            for (int j = 0; j < 4; ++j)
                acc[i][j] = MFMA_BF16(a[i], b[j], acc[i][j]);
    }

    const int r0 = (lane >> 4) * 4;
#pragma unroll
    for (int j = 0; j < 4; ++j) {
        const int n = nTile + wn + j * 16 + lm;
        const float bv = __bfloat162float(bias[n]);
#pragma unroll
        for (int i = 0; i < 4; ++i) {
#pragma unroll
            for (int r = 0; r < 4; ++r) {
                const size_t m = mTile + wm + i * 16 + r0 + r;
                const float v = acc[i][j][r] + bv;
                if (f32out) ((float*)outv)[m * DMODEL + n] = v;
                else ((__hip_bfloat16*)outv)[m * DMODEL + n] = __float2bfloat16(v);
            }
        }
    }
}

// ---------------------------------------------------------------------------
extern "C" void kernel_launch(void* const* d_in, const int* in_sizes, int n_in,
                              void* d_out, int out_size, void* d_ws, size_t ws_size,
                              hipStream_t stream) {
    // Workspace layout (bytes):
    //   [flag:256][canon bf16][Qs][Kb][Vt][Ao][Pm][Pl][Po]
    const size_t OFF_CANON = 256;
    const size_t OFF_QS = OFF_CANON + (size_t)N_CANON * 2;
    const size_t OFF_KB = OFF_QS + (size_t)NTOK * DMODEL * 2;
    const size_t OFF_VT = OFF_KB + (size_t)NTOK * DMODEL * 2;
    const size_t OFF_AO = OFF_VT + (size_t)NTOK * DMODEL * 2;
    const size_t OFF_PM = OFF_AO + (size_t)NTOK * DMODEL * 2;
    const size_t NSLOT  = (size_t)NUNITS;                            // 5120
    const size_t OFF_PL = OFF_PM + NSLOT * 32 * 4;
    const size_t OFF_PO = OFF_PL + NSLOT * 32 * 4;
    const size_t NEED_F32 = OFF_PO + NSLOT * 2048 * 4;               // ~93.6 MB
    const size_t NEED_BF  = OFF_PO + NSLOT * 2048 * 2;               // ~72.6 MB

    char* wsb = (char*)d_ws;
    int* flag = (int*)wsb;
    __hip_bfloat16* canon = (__hip_bfloat16*)(wsb + OFF_CANON);
    __hip_bfloat16* Xc = canon;
    __hip_bfloat16* Wq = Xc + N_X;
    __hip_bfloat16* Bq = Wq + N_WQ;
    __hip_bfloat16* Wo = Bq + N_BQ;
    __hip_bfloat16* Bo = Wo + N_WO;
    __hip_bfloat16* Qs = (__hip_bfloat16*)(wsb + OFF_QS);
    __hip_bfloat16* Kb = (__hip_bfloat16*)(wsb + OFF_KB);
    __hip_bfloat16* Vt = (__hip_bfloat16*)(wsb + OFF_VT);
    __hip_bfloat16* Ao = (__hip_bfloat16*)(wsb + OFF_AO);
    float* Pm = (float*)(wsb + OFF_PM);
    float* Pl = (float*)(wsb + OFF_PL);

    // 0) dtype detect + canonicalize
    detect_kernel<<<1, 64, 0, stream>>>((const unsigned short*)d_in[1], flag);
    canon_kernel<<<(N_CANON + 255) / 256, 256, 0, stream>>>(
        d_in[0], d_in[1], d_in[2], d_in[3], d_in[4], canon, flag);

    // 1) QKV GEMM
    {
        dim3 grid(3 * DMODEL / 128, NTOK / 128);
        qkv_gemm_kernel<<<grid, 256, 0, stream>>>(Xc, Wq, Bq, Qs, Kb, Vt);
    }
    // 2) Attention: compact split-K (8 waves per 512-thread WG) or fallback
    if (ws_size >= NEED_BF) {
        dim3 gseg(NUNITS / 8);          // 640 WGs
        dim3 gcmb(SEQ / 32, BATCH * NHEAD);
        if (ws_size >= NEED_F32) {
            float* Po = (float*)(wsb + OFF_PO);
            attn_seg_kernel<float><<<gseg, 512, 0, stream>>>(Qs, Kb, Vt, Po, Pm, Pl);
            attn_combine_kernel<float><<<gcmb, 64, 0, stream>>>(Po, Pm, Pl, Ao);
        } else {
            unsigned short* Po = (unsigned short*)(wsb + OFF_PO);
            attn_seg_kernel<unsigned short><<<gseg, 512, 0, stream>>>(Qs, Kb, Vt, Po, Pm, Pl);
            attn_combine_kernel<unsigned short><<<gcmb, 64, 0, stream>>>(Po, Pm, Pl, Ao);
        }
    } else {
        dim3 grid(SEQ / 32, BATCH * NHEAD);
        attn_kernel<<<grid, 64, 0, stream>>>(Qs, Kb, Vt, Ao);
    }
    // 3) Out projection
    {
        dim3 grid(DMODEL / 128, NTOK / 128);
        proj_gemm_kernel<<<grid, 256, 0, stream>>>(Ao, Wo, Bo, d_out, flag);
    }
}

// Round 11
// 231.557 us; speedup vs baseline: 1.1878x; 1.1878x over previous
//
#include <hip/hip_runtime.h>
#include <hip/hip_bf16.h>

// Sizes (fixed): B=2, S=2048, D=1024, H=16, Hd=64
#define SEQ    2048
#define DMODEL 1024
#define NHEAD  16
#define HDIM   64
#define BATCH  2
#define NTOK   (BATCH * SEQ)           // 4096

#define N_X   (NTOK * DMODEL)
#define N_WQ  (3 * DMODEL * DMODEL)
#define N_BQ  (3 * DMODEL)
#define N_WO  (DMODEL * DMODEL)
#define N_BO  (DMODEL)
#define N_CANON (N_X + N_WQ + N_BQ + N_WO + N_BO)   // 8,392,704

#define NEG_SENT (-1.0e30f)
#define QSCALE 0.1803368801111f        // (1/8) * log2(e)

typedef __attribute__((ext_vector_type(8))) short short8;
typedef __attribute__((ext_vector_type(4))) short short4v;
typedef __attribute__((ext_vector_type(4))) float f32x4;

#define MFMA_BF16(A, B, C) __builtin_amdgcn_mfma_f32_16x16x32_bf16((A), (B), (C), 0, 0, 0)

static __device__ __forceinline__ short8 load8(const __hip_bfloat16* p) {
    return *(const short8*)p;
}

static __device__ __forceinline__ void async16(const void* g, void* l) {
    __builtin_amdgcn_global_load_lds(
        (const __attribute__((address_space(1))) unsigned int*)g,
        (__attribute__((address_space(3))) unsigned int*)l,
        16, 0, 0);
}

// ---------------------------------------------------------------------------
// Kernel 0: dtype detector (confirmed fp32 in round 2; keep for robustness)
// ---------------------------------------------------------------------------
__global__ void detect_kernel(const unsigned short* __restrict__ w, int* flag) {
    int cnt = 0;
    for (int i = threadIdx.x; i < 512; i += 64) {
        const unsigned e = (w[i] >> 7) & 0xFF;
        if (e >= 125) cnt++;
    }
#pragma unroll
    for (int o = 32; o; o >>= 1) cnt += __shfl_down(cnt, o);
    if (threadIdx.x == 0) *flag = (cnt > 8) ? 1 : 0;
}

// ---------------------------------------------------------------------------
// Kernel 0b: canonicalize inputs to bf16: [X | Wqkv | bqkv | Wout | bout]
// ---------------------------------------------------------------------------
__global__ __launch_bounds__(256) void canon_kernel(
    const void* __restrict__ s0, const void* __restrict__ s1,
    const void* __restrict__ s2, const void* __restrict__ s3,
    const void* __restrict__ s4,
    __hip_bfloat16* __restrict__ dst, const int* __restrict__ flag)
{
    const int idx = blockIdx.x * 256 + threadIdx.x;
    if (idx >= N_CANON) return;
    const void* src;
    int off;
    if (idx < N_X)                         { src = s0; off = idx; }
    else if (idx < N_X + N_WQ)             { src = s1; off = idx - N_X; }
    else if (idx < N_X + N_WQ + N_BQ)      { src = s2; off = idx - (N_X + N_WQ); }
    else if (idx < N_X + N_WQ + N_BQ + N_WO){ src = s3; off = idx - (N_X + N_WQ + N_BQ); }
    else                                   { src = s4; off = idx - (N_X + N_WQ + N_BQ + N_WO); }
    const bool isf32 = (*flag != 0);
    const float v = isf32 ? ((const float*)src)[off]
                          : __bfloat162float(((const __hip_bfloat16*)src)[off]);
    dst[idx] = __float2bfloat16(v);
}

// ---------------------------------------------------------------------------
// Kernel 1: QKV GEMM, m97 structure (128x128 tile, global_load_lds w=16).
// ---------------------------------------------------------------------------
__global__ __launch_bounds__(256) void qkv_gemm_kernel(
    const __hip_bfloat16* __restrict__ X,
    const __hip_bfloat16* __restrict__ W,
    const __hip_bfloat16* __restrict__ bias,
    __hip_bfloat16* __restrict__ Qs,
    __hip_bfloat16* __restrict__ Kb,
    __hip_bfloat16* __restrict__ Vt)
{
    constexpr int Kd = DMODEL;
    __shared__ __align__(16) __hip_bfloat16 As[128 * 32];
    __shared__ __align__(16) __hip_bfloat16 Bs[128 * 32];

    const int tid   = threadIdx.x;
    const int lane  = tid & 63;
    const int w     = tid >> 6;
    const int mTile = blockIdx.y * 128;
    const int nTile = blockIdx.x * 128;
    const int wm    = (w >> 1) * 64;
    const int wn    = (w & 1) * 64;
    const int lm    = lane & 15;
    const int lk    = (lane >> 4) * 8;

    f32x4 acc[4][4];
#pragma unroll
    for (int i = 0; i < 4; ++i)
#pragma unroll
        for (int j = 0; j < 4; ++j)
            acc[i][j] = (f32x4){0.f, 0.f, 0.f, 0.f};

    const int r0c = tid >> 2, p0c = tid & 3;
    const int r1c = (tid + 256) >> 2, p1c = tid & 3;

    for (int k0 = 0; k0 < Kd; k0 += 32) {
        __syncthreads();
        async16(&X[(size_t)(mTile + r0c) * Kd + k0 + p0c * 8], (char*)As + tid * 16);
        async16(&X[(size_t)(mTile + r1c) * Kd + k0 + p1c * 8], (char*)As + tid * 16 + 4096);
        async16(&W[(size_t)(nTile + r0c) * Kd + k0 + p0c * 8], (char*)Bs + tid * 16);
        async16(&W[(size_t)(nTile + r1c) * Kd + k0 + p1c * 8], (char*)Bs + tid * 16 + 4096);
        __syncthreads();

        short8 a[4], b[4];
#pragma unroll
        for (int i = 0; i < 4; ++i)
            a[i] = *(const short8*)&As[(wm + i * 16 + lm) * 32 + lk];
#pragma unroll
        for (int j = 0; j < 4; ++j)
            b[j] = *(const short8*)&Bs[(wn + j * 16 + lm) * 32 + lk];
#pragma unroll
        for (int i = 0; i < 4; ++i)
#pragma unroll
            for (int j = 0; j < 4; ++j)
                acc[i][j] = MFMA_BF16(a[i], b[j], acc[i][j]);
    }

    const int r0 = (lane >> 4) * 4;
#pragma unroll
    for (int j = 0; j < 4; ++j) {
        const int n  = nTile + wn + j * 16 + lm;
        const float bv = __bfloat162float(bias[n]);
        const int c = n >> 10;
        const int h = (n >> 6) & 15;
        const int d = n & 63;
#pragma unroll
        for (int i = 0; i < 4; ++i) {
#pragma unroll
            for (int r = 0; r < 4; ++r) {
                const int m  = mTile + wm + i * 16 + r0 + r;
                const int bb = m >> 11;
                const int s  = m & (SEQ - 1);
                const int bh = bb * NHEAD + h;
                const float v = acc[i][j][r] + bv;
                if (c == 0) {
                    Qs[(size_t)(bh * SEQ + s) * HDIM + d] = __float2bfloat16(v * QSCALE);
                } else if (c == 1) {
                    Kb[(size_t)(bh * SEQ + s) * HDIM + d] = __float2bfloat16(v);
                } else {
                    Vt[(size_t)(bh * HDIM + d) * SEQ + s] = __float2bfloat16(v);
                }
            }
        }
    }
}

// ---------------------------------------------------------------------------
// Kernel 2: cooperative causal flash attention, PAIR-BALANCED.
// nChunks(qb) = 2*(qb+1), qb in [0,16).  Pair (15-p, p): sum = 34 for every
// pair -> all 256 WGs identical length, zero tail (round 9's 89 us was
// tail-dominated: heavy 32-chunk WGs serialized at 1 WG/CU at the end).
// Heavy block first so the light block's K/V (subset of heavy's range) are
// L2-warm.  Per-phase body identical to round 9.
// WG = 256 thr = 4 waves = 128 q rows (wave w owns rows qbase + w*32 .. +31).
// K tile [64 k][64 d] + V tile [64 d][64 k] staged via global_load_lds w=16,
// XOR-block swizzle (slot = cb ^ (row&7)) -> conflict-free ds_read_b128.
// ---------------------------------------------------------------------------
#define P_PITCH 72
__global__ __launch_bounds__(256, 2) void attn_kernel(
    const __hip_bfloat16* __restrict__ Qs,  // [B,H,S,Hd], pre-scaled
    const __hip_bfloat16* __restrict__ Kb,  // [B,H,S,Hd]
    const __hip_bfloat16* __restrict__ Vt,  // [B,H,Hd,S]
    __hip_bfloat16* __restrict__ O)         // [B*S, D]
{
    __shared__ __align__(16) __hip_bfloat16 Kt[64 * 64];
    __shared__ __align__(16) __hip_bfloat16 Vs[64 * 64];
    __shared__ __align__(16) __hip_bfloat16 Pall[4][32 * P_PITCH];

    const int lane = threadIdx.x & 63;
    const int wv   = threadIdx.x >> 6;
    const int pr   = blockIdx.x;            // pair index 0..7
    const int bh   = blockIdx.y;

    const int lm  = lane & 15;
    const int q4  = lane >> 4;
    const int lk  = q4 * 8;
    const int swz = (lm & 3) << 4;

    __hip_bfloat16* P = Pall[wv];

    const __hip_bfloat16* Qbh = Qs + (size_t)bh * SEQ * HDIM;
    const __hip_bfloat16* Kbh = Kb + (size_t)bh * SEQ * HDIM;
    const __hip_bfloat16* Vbh = Vt + (size_t)bh * HDIM * SEQ;

    // staging address components (loop-invariant)
    const int srow = (lane >> 3);          // row-rel within 8-row slab
    const int scb  = (lane & 7) ^ srow;    // global column-block to fetch
    const int krow0 = wv * 16 + srow;
    const int krow1 = wv * 16 + 8 + srow;

    const int b  = bh >> 4;
    const int hh = bh & 15;

    for (int ph = 0; ph < 2; ++ph) {
        const int qb    = ph ? pr : 15 - pr;   // heavy first, then light
        const int qbase = qb * 128;
        const int wbase = qbase + wv * 32;

        short8 qa[2][2];
#pragma unroll
        for (int i = 0; i < 2; ++i)
#pragma unroll
            for (int h = 0; h < 2; ++h)
                qa[i][h] = load8(&Qbh[(size_t)(wbase + i * 16 + lm) * HDIM + h * 32 + lk]);

        float m_run[2] = {NEG_SENT, NEG_SENT};
        float l_run[2] = {0.f, 0.f};
        f32x4 Oacc[2][4];
#pragma unroll
        for (int i = 0; i < 2; ++i)
#pragma unroll
            for (int t = 0; t < 4; ++t) Oacc[i][t] = (f32x4){0.f, 0.f, 0.f, 0.f};

        const int nChunks = 2 * (qb + 1);
        for (int c = 0; c < nChunks; ++c) {
            const int k0 = c * 64;

            __syncthreads();   // all waves done reading previous tiles
            async16(&Kbh[(size_t)(k0 + krow0) * HDIM + scb * 8],
                    (char*)Kt + (size_t)(wv * 16) * 128 + (lane * 16));
            async16(&Kbh[(size_t)(k0 + krow1) * HDIM + scb * 8],
                    (char*)Kt + (size_t)(wv * 16 + 8) * 128 + (lane * 16));
            async16(&Vbh[(size_t)krow0 * SEQ + k0 + scb * 8],
                    (char*)Vs + (size_t)(wv * 16) * 128 + (lane * 16));
            async16(&Vbh[(size_t)krow1 * SEQ + k0 + scb * 8],
                    (char*)Vs + (size_t)(wv * 16 + 8) * 128 + (lane * 16));
            __syncthreads();   // tiles visible

            if (k0 <= wbase + 31) {   // not fully masked for this wave
                short8 ka[4][2];
#pragma unroll
                for (int t = 0; t < 4; ++t)
#pragma unroll
                    for (int h = 0; h < 2; ++h)
                        ka[t][h] = *(const short8*)&Kt[(t * 16 + lm) * 64 +
                                                       (((h * 4 + q4) ^ (lm & 7)) * 8)];

                f32x4 sc[2][4];
#pragma unroll
                for (int i = 0; i < 2; ++i)
#pragma unroll
                    for (int t = 0; t < 4; ++t) sc[i][t] = (f32x4){0.f, 0.f, 0.f, 0.f};
#pragma unroll
                for (int t = 0; t < 4; ++t)
#pragma unroll
                    for (int i = 0; i < 2; ++i) {
                        sc[i][t] = MFMA_BF16(ka[t][0], qa[i][0], sc[i][t]);
                        sc[i][t] = MFMA_BF16(ka[t][1], qa[i][1], sc[i][t]);
                    }

                if (k0 + 63 > wbase) {
#pragma unroll
                    for (int i = 0; i < 2; ++i) {
                        const int row = wbase + i * 16 + lm;
#pragma unroll
                        for (int t = 0; t < 4; ++t)
#pragma unroll
                            for (int r = 0; r < 4; ++r) {
                                const int key = k0 + t * 16 + q4 * 4 + r;
                                if (key > row) sc[i][t][r] = NEG_SENT;
                            }
                    }
                }

                float alpha[2];
#pragma unroll
                for (int i = 0; i < 2; ++i) {
                    float mx = sc[i][0][0];
#pragma unroll
                    for (int t = 0; t < 4; ++t)
#pragma unroll
                        for (int r = 0; r < 4; ++r) mx = fmaxf(mx, sc[i][t][r]);
                    mx = fmaxf(mx, __shfl_xor(mx, 16));
                    mx = fmaxf(mx, __shfl_xor(mx, 32));
                    const float mn = fmaxf(m_run[i], mx);
                    alpha[i] = exp2f(m_run[i] - mn);
                    float s = 0.f;
#pragma unroll
                    for (int t = 0; t < 4; ++t)
#pragma unroll
                        for (int r = 0; r < 4; ++r) {
                            const float p = exp2f(sc[i][t][r] - mn);
                            sc[i][t][r] = p;
                            s += p;
                        }
                    s += __shfl_xor(s, 16);
                    s += __shfl_xor(s, 32);
                    l_run[i] = l_run[i] * alpha[i] + s;
                    m_run[i] = mn;
                }

#pragma unroll
                for (int i = 0; i < 2; ++i)
#pragma unroll
                    for (int r = 0; r < 4; ++r) {
                        const float av = __shfl(alpha[i], q4 * 4 + r);
#pragma unroll
                        for (int t = 0; t < 4; ++t) Oacc[i][t][r] *= av;
                    }

#pragma unroll
                for (int i = 0; i < 2; ++i)
#pragma unroll
                    for (int t = 0; t < 4; ++t) {
                        short4v pk;
#pragma unroll
                        for (int r = 0; r < 4; ++r)
                            pk[r] = (short)__bfloat16_as_ushort(__float2bfloat16(sc[i][t][r]));
                        const int col = (t * 16 + q4 * 4) ^ swz;
                        *(short4v*)&P[(i * 16 + lm) * P_PITCH + col] = pk;
                    }

#pragma unroll
                for (int h = 0; h < 2; ++h) {
                    short8 pa[2];
#pragma unroll
                    for (int i = 0; i < 2; ++i) {
                        const int col = (h * 32 + lk) ^ swz;
                        pa[i] = *(const short8*)&P[(i * 16 + lm) * P_PITCH + col];
                    }
#pragma unroll
                    for (int t = 0; t < 4; ++t) {
                        const short8 vb = *(const short8*)&Vs[(t * 16 + lm) * 64 +
                                                              (((h * 4 + q4) ^ (lm & 7)) * 8)];
#pragma unroll
                        for (int i = 0; i < 2; ++i)
                            Oacc[i][t] = MFMA_BF16(pa[i], vb, Oacc[i][t]);
                    }
                }
            }
        }

        // --- epilogue for this phase's 128 q-rows ---
#pragma unroll
        for (int i = 0; i < 2; ++i)
#pragma unroll
            for (int r = 0; r < 4; ++r) {
                const float lv = __shfl(l_run[i], q4 * 4 + r);
                const float inv = 1.0f / lv;
                const size_t m = (size_t)b * SEQ + wbase + i * 16 + q4 * 4 + r;
#pragma unroll
                for (int t = 0; t < 4; ++t)
                    O[m * DMODEL + hh * 64 + t * 16 + lm] = __float2bfloat16(Oacc[i][t][r] * inv);
            }
    }
}

// ---------------------------------------------------------------------------
// Kernel 3: out projection, m97 structure.
// ---------------------------------------------------------------------------
__global__ __launch_bounds__(256) void proj_gemm_kernel(
    const __hip_bfloat16* __restrict__ A,
    const __hip_bfloat16* __restrict__ W,
    const __hip_bfloat16* __restrict__ bias,
    void* __restrict__ outv,
    const int* __restrict__ flag)
{
    constexpr int Kd = DMODEL;
    __shared__ __align__(16) __hip_bfloat16 As[128 * 32];
    __shared__ __align__(16) __hip_bfloat16 Bs[128 * 32];

    const int tid   = threadIdx.x;
    const int lane  = tid & 63;
    const int w     = tid >> 6;
    const int mTile = blockIdx.y * 128;
    const int nTile = blockIdx.x * 128;
    const int wm    = (w >> 1) * 64;
    const int wn    = (w & 1) * 64;
    const int lm    = lane & 15;
    const int lk    = (lane >> 4) * 8;
    const bool f32out = (*flag != 0);

    f32x4 acc[4][4];
#pragma unroll
    for (int i = 0; i < 4; ++i)
#pragma unroll
        for (int j = 0; j < 4; ++j)
            acc[i][j] = (f32x4){0.f, 0.f, 0.f, 0.f};

    const int r0c = tid >> 2, p0c = tid & 3;
    const int r1c = (tid + 256) >> 2, p1c = tid & 3;

    for (int k0 = 0; k0 < Kd; k0 += 32) {
        __syncthreads();
        async16(&A[(size_t)(mTile + r0c) * Kd + k0 + p0c * 8], (char*)As + tid * 16);
        async16(&A[(size_t)(mTile + r1c) * Kd + k0 + p1c * 8], (char*)As + tid * 16 + 4096);
        async16(&W[(size_t)(nTile + r0c) * Kd + k0 + p0c * 8], (char*)Bs + tid * 16);
        async16(&W[(size_t)(nTile + r1c) * Kd + k0 + p1c * 8], (char*)Bs + tid * 16 + 4096);
        __syncthreads();

        short8 a[4], b[4];
#pragma unroll
        for (int i = 0; i < 4; ++i)
            a[i] = *(const short8*)&As[(wm + i * 16 + lm) * 32 + lk];
#pragma unroll
        for (int j = 0; j < 4; ++j)
            b[j] = *(const short8*)&Bs[(wn + j * 16 + lm) * 32 + lk];
#pragma unroll
        for (int i = 0; i < 4; ++i)
#pragma unroll
            for (int j = 0; j < 4; ++j)
                acc[i][j] = MFMA_BF16(a[i], b[j], acc[i][j]);
    }

    const int r0 = (lane >> 4) * 4;
#pragma unroll
    for (int j = 0; j < 4; ++j) {
        const int n = nTile + wn + j * 16 + lm;
        const float bv = __bfloat162float(bias[n]);
#pragma unroll
        for (int i = 0; i < 4; ++i) {
#pragma unroll
            for (int r = 0; r < 4; ++r) {
                const size_t m = mTile + wm + i * 16 + r0 + r;
                const float v = acc[i][j][r] + bv;
                if (f32out) ((float*)outv)[m * DMODEL + n] = v;
                else ((__hip_bfloat16*)outv)[m * DMODEL + n] = __float2bfloat16(v);
            }
        }
    }
}

// ---------------------------------------------------------------------------
extern "C" void kernel_launch(void* const* d_in, const int* in_sizes, int n_in,
                              void* d_out, int out_size, void* d_ws, size_t ws_size,
                              hipStream_t stream) {
    // Workspace layout (bytes): [flag:256][canon bf16][Qs][Kb][Vt][Ao]
    const size_t OFF_CANON = 256;
    const size_t OFF_QS = OFF_CANON + (size_t)N_CANON * 2;
    const size_t OFF_KB = OFF_QS + (size_t)NTOK * DMODEL * 2;
    const size_t OFF_VT = OFF_KB + (size_t)NTOK * DMODEL * 2;
    const size_t OFF_AO = OFF_VT + (size_t)NTOK * DMODEL * 2;

    char* wsb = (char*)d_ws;
    int* flag = (int*)wsb;
    __hip_bfloat16* canon = (__hip_bfloat16*)(wsb + OFF_CANON);
    __hip_bfloat16* Xc = canon;
    __hip_bfloat16* Wq = Xc + N_X;
    __hip_bfloat16* Bq = Wq + N_WQ;
    __hip_bfloat16* Wo = Bq + N_BQ;
    __hip_bfloat16* Bo = Wo + N_WO;
    __hip_bfloat16* Qs = (__hip_bfloat16*)(wsb + OFF_QS);
    __hip_bfloat16* Kb = (__hip_bfloat16*)(wsb + OFF_KB);
    __hip_bfloat16* Vt = (__hip_bfloat16*)(wsb + OFF_VT);
    __hip_bfloat16* Ao = (__hip_bfloat16*)(wsb + OFF_AO);

    // 0) dtype detect + canonicalize
    detect_kernel<<<1, 64, 0, stream>>>((const unsigned short*)d_in[1], flag);
    canon_kernel<<<(N_CANON + 255) / 256, 256, 0, stream>>>(
        d_in[0], d_in[1], d_in[2], d_in[3], d_in[4], canon, flag);

    // 1) QKV GEMM
    {
        dim3 grid(3 * DMODEL / 128, NTOK / 128);
        qkv_gemm_kernel<<<grid, 256, 0, stream>>>(Xc, Wq, Bq, Qs, Kb, Vt);
    }
    // 2) Attention: pair-balanced cooperative blocks, grid (8, B*H) = 256 WGs
    {
        dim3 grid(8, BATCH * NHEAD);
        attn_kernel<<<grid, 256, 0, stream>>>(Qs, Kb, Vt, Ao);
    }
    // 3) Out projection
    {
        dim3 grid(DMODEL / 128, NTOK / 128);
        proj_gemm_kernel<<<grid, 256, 0, stream>>>(Ao, Wo, Bo, d_out, flag);
    }
}